// Round 4
// baseline (2351.382 us; speedup 1.0000x reference)
//
#include <hip/hip_runtime.h>
#include <math.h>

typedef unsigned int uint32;
typedef unsigned short u16;
typedef __attribute__((ext_vector_type(8))) short short8;
typedef __attribute__((ext_vector_type(4))) float float4v;

#define CIN 128
#define HID 256
#define COUT 40
#define KPROP 10
#define NSLICE 4   // 4 slices x 32 channels; row-slice = 64 B = one cache line
#define ONE_MINUS_ALPHA 0.95f
#define PPR_ALPHA 0.05f
#define SCAN_CHUNK 1024

__device__ inline u16 f2bf(float f) {
  uint32 u = __float_as_uint(f);
  u += 0x7fffu + ((u >> 16) & 1u);
  return (u16)(u >> 16);
}
__device__ inline float bflo(uint32 w) { return __uint_as_float(w << 16); }
__device__ inline float bfhi(uint32 w) { return __uint_as_float(w & 0xffff0000u); }

// ---------------- CSR build ----------------

__global__ void hist_kernel(const int* __restrict__ src, int* __restrict__ cnt, int E) {
  int i = blockIdx.x * blockDim.x + threadIdx.x;
  int stride = gridDim.x * blockDim.x;
  for (; i < E; i += stride) atomicAdd(&cnt[src[i]], 1);
}

__global__ void chunk_sum_kernel(const int* __restrict__ cnt, int* __restrict__ bsum, int n) {
  __shared__ int smem[256];
  int b = blockIdx.x, t = threadIdx.x;
  int base = b * SCAN_CHUNK;
  int s = 0;
  for (int k = 0; k < 4; ++k) {
    int idx = base + t + k * 256;
    if (idx < n) s += cnt[idx];
  }
  smem[t] = s;
  __syncthreads();
  for (int off = 128; off > 0; off >>= 1) {
    if (t < off) smem[t] += smem[t + off];
    __syncthreads();
  }
  if (t == 0) bsum[b] = smem[0];
}

__global__ void bsum_scan_kernel(int* bsum, int nb) {
  __shared__ int sm[1024];
  int t = threadIdx.x;
  int v = (t < nb) ? bsum[t] : 0;
  sm[t] = v;
  __syncthreads();
  for (int off = 1; off < 1024; off <<= 1) {
    int add = (t >= off) ? sm[t - off] : 0;
    __syncthreads();
    sm[t] += add;
    __syncthreads();
  }
  if (t < nb) bsum[t] = sm[t] - v;  // exclusive
}

__global__ void chunk_scan_kernel(const int* __restrict__ cnt, const int* __restrict__ bsum,
                                  int* __restrict__ rowptr, int n) {
  __shared__ int smem[256];
  int b = blockIdx.x, t = threadIdx.x;
  int base = b * SCAN_CHUNK + t * 4;
  int v[4];
  for (int k = 0; k < 4; ++k) v[k] = (base + k < n) ? cnt[base + k] : 0;
  int s = v[0] + v[1] + v[2] + v[3];
  smem[t] = s;
  __syncthreads();
  for (int off = 1; off < 256; off <<= 1) {
    int add = (t >= off) ? smem[t - off] : 0;
    __syncthreads();
    smem[t] += add;
    __syncthreads();
  }
  int run = bsum[b] + smem[t] - s;
  for (int k = 0; k < 4; ++k) {
    run += v[k];
    if (base + k < n) rowptr[base + k + 1] = run;
  }
  if (b == 0 && t == 0) rowptr[0] = 0;
}

__global__ void scatter_kernel(const int* __restrict__ src, const int* __restrict__ dst,
                               int* __restrict__ cursor, int* __restrict__ cols, int E) {
  int i = blockIdx.x * blockDim.x + threadIdx.x;
  int stride = gridDim.x * blockDim.x;
  for (; i < E; i += stride) {
    int pos = atomicAdd(&cursor[src[i]], 1);
    cols[pos] = dst[i];
  }
}

// ---------------- prep: casts + weight packing ----------------

// x [N][128] f32 -> xb 4 planes [s][N][32] bf16. One thread = one uint4 (8 ch).
__global__ void cvt_slice_kernel(const float* __restrict__ in, u16* __restrict__ out, int n) {
  int idx = blockIdx.x * blockDim.x + threadIdx.x;
  if (idx >= n * 16) return;
  int node = idx >> 4;
  int q = idx & 15;
  int s = q >> 2;     // slice
  int quad = q & 3;   // 8-channel group within slice
  const float4* xin = (const float4*)(in + (size_t)node * CIN + s * 32 + quad * 8);
  float4 v0 = xin[0];
  float4 v1 = xin[1];
  uint4 r;
  r.x = (uint32)f2bf(v0.x) | ((uint32)f2bf(v0.y) << 16);
  r.y = (uint32)f2bf(v0.z) | ((uint32)f2bf(v0.w) << 16);
  r.z = (uint32)f2bf(v1.x) | ((uint32)f2bf(v1.y) << 16);
  r.w = (uint32)f2bf(v1.z) | ((uint32)f2bf(v1.w) << 16);
  ((uint4*)out)[(size_t)s * n * 4 + (size_t)node * 4 + quad] = r;
}

// W1P: B-fragment packed, 0.05 folded in. idx = ((kk*16+nt)*64+l)*8+j8
__global__ void pack_w1_kernel(const float* __restrict__ W1, u16* __restrict__ W1P) {
  int idx = blockIdx.x * blockDim.x + threadIdx.x;
  if (idx >= 4 * 16 * 64 * 8) return;
  int j8 = idx & 7;
  int l = (idx >> 3) & 63;
  int nt = (idx >> 9) & 15;
  int kk = idx >> 13;
  int k = kk * 32 + (l >> 4) * 8 + j8;
  int nn = nt * 16 + (l & 15);
  W1P[idx] = f2bf(PPR_ALPHA * W1[nn * CIN + k]);
}

// W2P: idx = ((kk2*3+nt2)*64+l)*8+j8
__global__ void pack_w2_kernel(const float* __restrict__ W2, u16* __restrict__ W2P) {
  int idx = blockIdx.x * blockDim.x + threadIdx.x;
  if (idx >= 8 * 3 * 64 * 8) return;
  int j8 = idx & 7;
  int l = (idx >> 3) & 63;
  int nt2 = (idx >> 9) % 3;
  int kk2 = (idx >> 9) / 3;
  int k = kk2 * 32 + (l >> 4) * 8 + j8;
  int o = nt2 * 16 + (l & 15);
  W2P[idx] = (o < COUT) ? f2bf(W2[o * HID + k]) : (u16)0;
}

// ---------------- channel-sliced propagation ----------------
// One 32-channel plane (64 B/row). Wave per node: eg = lane>>2 (16 edge
// groups), ch = lane&3 (4 x 16 B = one 64-B line per row). A wave-load
// gathers 16 rows x 64 B. Per-dispatch gather working set = 6.4 MB ->
// mostly resident in each XCD's 4 MiB L2.

__global__ __launch_bounds__(256) void prop_slice_kernel(
    const u16* __restrict__ uin, const u16* __restrict__ xp, u16* __restrict__ uout,
    const int* __restrict__ rowptr, const int* __restrict__ cols, int n) {
  int wid = threadIdx.x >> 6;
  int lane = threadIdx.x & 63;
  int node = blockIdx.x * 4 + wid;
  if (node >= n) return;
  int eg = lane >> 2;   // 0..15
  int ch = lane & 3;    // 0..3
  int start = rowptr[node], end = rowptr[node + 1];
  const uint4* uw4 = (const uint4*)uin;  // row = 4 uint4

  float acc[8];
  if (eg == 0) {  // self-loop, counted once
    uint4 s = uw4[(size_t)node * 4 + ch];
    acc[0] = bflo(s.x); acc[1] = bfhi(s.x);
    acc[2] = bflo(s.y); acc[3] = bfhi(s.y);
    acc[4] = bflo(s.z); acc[5] = bfhi(s.z);
    acc[6] = bflo(s.w); acc[7] = bfhi(s.w);
  } else {
#pragma unroll
    for (int j = 0; j < 8; ++j) acc[j] = 0.f;
  }

  int e = start;
  for (; e + 32 <= end; e += 32) {
    int d0 = cols[e + eg];
    int d1 = cols[e + 16 + eg];
    uint4 w0 = uw4[(size_t)d0 * 4 + ch];
    uint4 w1 = uw4[(size_t)d1 * 4 + ch];
    acc[0] += bflo(w0.x); acc[1] += bfhi(w0.x);
    acc[2] += bflo(w0.y); acc[3] += bfhi(w0.y);
    acc[4] += bflo(w0.z); acc[5] += bfhi(w0.z);
    acc[6] += bflo(w0.w); acc[7] += bfhi(w0.w);
    acc[0] += bflo(w1.x); acc[1] += bfhi(w1.x);
    acc[2] += bflo(w1.y); acc[3] += bfhi(w1.y);
    acc[4] += bflo(w1.z); acc[5] += bfhi(w1.z);
    acc[6] += bflo(w1.w); acc[7] += bfhi(w1.w);
  }
  for (; e + 16 <= end; e += 16) {
    int d0 = cols[e + eg];
    uint4 w0 = uw4[(size_t)d0 * 4 + ch];
    acc[0] += bflo(w0.x); acc[1] += bfhi(w0.x);
    acc[2] += bflo(w0.y); acc[3] += bfhi(w0.y);
    acc[4] += bflo(w0.z); acc[5] += bfhi(w0.z);
    acc[6] += bflo(w0.w); acc[7] += bfhi(w0.w);
  }
  int rem = end - e;
  if (eg < rem) {
    int d0 = cols[e + eg];
    uint4 w0 = uw4[(size_t)d0 * 4 + ch];
    acc[0] += bflo(w0.x); acc[1] += bfhi(w0.x);
    acc[2] += bflo(w0.y); acc[3] += bfhi(w0.y);
    acc[4] += bflo(w0.z); acc[5] += bfhi(w0.z);
    acc[6] += bflo(w0.w); acc[7] += bfhi(w0.w);
  }

  // reduce across the 16 edge groups (same channels)
#pragma unroll
  for (int j = 0; j < 8; ++j) acc[j] += __shfl_xor(acc[j], 4, 64);
#pragma unroll
  for (int j = 0; j < 8; ++j) acc[j] += __shfl_xor(acc[j], 8, 64);
#pragma unroll
  for (int j = 0; j < 8; ++j) acc[j] += __shfl_xor(acc[j], 16, 64);
#pragma unroll
  for (int j = 0; j < 8; ++j) acc[j] += __shfl_xor(acc[j], 32, 64);

  if (eg == 0) {
    float c = ONE_MINUS_ALPHA / (float)(end - start + 1);
    uint4 xw = ((const uint4*)xp)[(size_t)node * 4 + ch];
    uint4 r;
    r.x = (uint32)f2bf(bflo(xw.x) + c * acc[0]) | ((uint32)f2bf(bfhi(xw.x) + c * acc[1]) << 16);
    r.y = (uint32)f2bf(bflo(xw.y) + c * acc[2]) | ((uint32)f2bf(bfhi(xw.y) + c * acc[3]) << 16);
    r.z = (uint32)f2bf(bflo(xw.z) + c * acc[4]) | ((uint32)f2bf(bfhi(xw.z) + c * acc[5]) << 16);
    r.w = (uint32)f2bf(bflo(xw.w) + c * acc[6]) | ((uint32)f2bf(bfhi(xw.w) + c * acc[7]) << 16);
    ((uint4*)uout)[(size_t)node * 4 + ch] = r;
  }
}

// ---------------- fused MFMA MLP + log_softmax ----------------
// u is 4 sliced planes [s][N][32]; slice index == mm1's kk index.

#define HPAD 264

__global__ __launch_bounds__(256, 2) void mlp_mfma_kernel(
    const u16* __restrict__ u, const u16* __restrict__ W1P, const float* __restrict__ b1,
    const u16* __restrict__ W2P, const float* __restrict__ b2,
    float* __restrict__ out, int n) {
  __shared__ __align__(16) u16 hS[128][HPAD];

  int t = threadIdx.x;
  int w = t >> 6, l = t & 63;
  int lg = l >> 4;
  int ln = l & 15;
  int node0 = blockIdx.x * 128;
  size_t pstride = (size_t)n * 4;  // plane stride in short8 units

  const short8* up = (const short8*)u;
  short8 a1[2][4];
#pragma unroll
  for (int mt = 0; mt < 2; ++mt) {
    int node = node0 + w * 32 + mt * 16 + ln;
    if (node >= n) node = n - 1;
#pragma unroll
    for (int kk = 0; kk < 4; ++kk)
      a1[mt][kk] = up[kk * pstride + (size_t)node * 4 + lg];
  }

  const short8* W1f = (const short8*)W1P;
  for (int nt = 0; nt < 16; ++nt) {
    short8 bfr[4];
#pragma unroll
    for (int kk = 0; kk < 4; ++kk) bfr[kk] = W1f[(kk * 16 + nt) * 64 + l];
    float bb = b1[nt * 16 + ln];
#pragma unroll
    for (int mt = 0; mt < 2; ++mt) {
      float4v c = {0.f, 0.f, 0.f, 0.f};
#pragma unroll
      for (int kk = 0; kk < 4; ++kk)
        c = __builtin_amdgcn_mfma_f32_16x16x32_bf16(a1[mt][kk], bfr[kk], c, 0, 0, 0);
#pragma unroll
      for (int r = 0; r < 4; ++r) {
        float h = fmaxf(c[r] + bb, 0.f);
        hS[w * 32 + mt * 16 + lg * 4 + r][nt * 16 + ln] = f2bf(h);
      }
    }
  }
  __syncthreads();

  const short8* W2f = (const short8*)W2P;
  float4v o2[2][3];
#pragma unroll
  for (int mt = 0; mt < 2; ++mt)
#pragma unroll
    for (int nt2 = 0; nt2 < 3; ++nt2) o2[mt][nt2] = (float4v){0.f, 0.f, 0.f, 0.f};
  for (int kk2 = 0; kk2 < 8; ++kk2) {
    short8 af[2];
#pragma unroll
    for (int mt = 0; mt < 2; ++mt)
      af[mt] = *(const short8*)&hS[w * 32 + mt * 16 + ln][kk2 * 32 + lg * 8];
    short8 bf0 = W2f[(kk2 * 3 + 0) * 64 + l];
    short8 bf1 = W2f[(kk2 * 3 + 1) * 64 + l];
    short8 bf2 = W2f[(kk2 * 3 + 2) * 64 + l];
#pragma unroll
    for (int mt = 0; mt < 2; ++mt) {
      o2[mt][0] = __builtin_amdgcn_mfma_f32_16x16x32_bf16(af[mt], bf0, o2[mt][0], 0, 0, 0);
      o2[mt][1] = __builtin_amdgcn_mfma_f32_16x16x32_bf16(af[mt], bf1, o2[mt][1], 0, 0, 0);
      o2[mt][2] = __builtin_amdgcn_mfma_f32_16x16x32_bf16(af[mt], bf2, o2[mt][2], 0, 0, 0);
    }
  }

  float b2v0 = b2[ln];
  float b2v1 = b2[16 + ln];
  bool v2 = (ln < 8);
  float b2v2 = v2 ? b2[32 + ln] : 0.f;
#pragma unroll
  for (int mt = 0; mt < 2; ++mt) {
#pragma unroll
    for (int r = 0; r < 4; ++r) {
      float x0 = o2[mt][0][r] + b2v0;
      float x1 = o2[mt][1][r] + b2v1;
      float x2 = v2 ? (o2[mt][2][r] + b2v2) : -INFINITY;
      float m = fmaxf(fmaxf(x0, x1), x2);
#pragma unroll
      for (int s = 1; s < 16; s <<= 1) m = fmaxf(m, __shfl_xor(m, s, 64));
      float es = __expf(x0 - m) + __expf(x1 - m) + (v2 ? __expf(x2 - m) : 0.f);
#pragma unroll
      for (int s = 1; s < 16; s <<= 1) es += __shfl_xor(es, s, 64);
      float lse = m + __logf(es);
      int node = node0 + w * 32 + mt * 16 + lg * 4 + r;
      if (node < n) {
        out[(size_t)node * COUT + ln] = x0 - lse;
        out[(size_t)node * COUT + 16 + ln] = x1 - lse;
        if (v2) out[(size_t)node * COUT + 32 + ln] = x2 - lse;
      }
    }
  }
}

// ---------------- launch ----------------

extern "C" void kernel_launch(void* const* d_in, const int* in_sizes, int n_in,
                              void* d_out, int out_size, void* d_ws, size_t ws_size,
                              hipStream_t stream) {
  const float* x = (const float*)d_in[0];
  const int* ei = (const int*)d_in[1];
  const float* W1 = (const float*)d_in[3];
  const float* b1 = (const float*)d_in[4];
  const float* W2 = (const float*)d_in[5];
  const float* b2 = (const float*)d_in[6];
  float* out = (float*)d_out;

  int N = in_sizes[0] / CIN;
  int E = in_sizes[1] / 2;
  const int* src = ei;
  const int* dst = ei + E;

  char* ws = (char*)d_ws;
  size_t off = 0;
  auto walloc = [&](size_t bytes) -> void* {
    void* p = ws + off;
    off += (bytes + 255) & ~(size_t)255;
    return p;
  };
  int* cnt = (int*)walloc((size_t)N * 4);
  int* rowptr = (int*)walloc(((size_t)N + 1) * 4);
  int* cursor = (int*)walloc((size_t)N * 4);
  int* bsum = (int*)walloc(1024 * 4);
  int* cols = (int*)walloc((size_t)E * 4);
  u16* W1P = (u16*)walloc((size_t)4 * 16 * 64 * 8 * 2);
  u16* W2P = (u16*)walloc((size_t)8 * 3 * 64 * 8 * 2);
  u16* xb = (u16*)walloc((size_t)N * CIN * 2);  // 4 planes [s][N][32]
  u16* u0 = (u16*)walloc((size_t)N * CIN * 2);
  u16* u1 = (u16*)walloc((size_t)N * CIN * 2);
  (void)ws_size; (void)n_in; (void)out_size;

  // CSR build (counting sort by src)
  hipMemsetAsync(cnt, 0, (size_t)N * 4, stream);
  hist_kernel<<<2048, 256, 0, stream>>>(src, cnt, E);
  int nchunks = (N + SCAN_CHUNK - 1) / SCAN_CHUNK;
  chunk_sum_kernel<<<nchunks, 256, 0, stream>>>(cnt, bsum, N);
  bsum_scan_kernel<<<1, 1024, 0, stream>>>(bsum, nchunks);
  chunk_scan_kernel<<<nchunks, 256, 0, stream>>>(cnt, bsum, rowptr, N);
  hipMemcpyAsync(cursor, rowptr, (size_t)N * 4, hipMemcpyDeviceToDevice, stream);
  scatter_kernel<<<2048, 256, 0, stream>>>(src, dst, cursor, cols, E);

  // prep
  cvt_slice_kernel<<<(N * 16 + 255) / 256, 256, 0, stream>>>(x, xb, N);
  pack_w1_kernel<<<(4 * 16 * 64 * 8 + 255) / 256, 256, 0, stream>>>(W1, W1P);
  pack_w2_kernel<<<(8 * 3 * 64 * 8 + 255) / 256, 256, 0, stream>>>(W2, W2P);

  // Horner PPR per channel slice: u_s <- x_s + 0.95 * P u_s  (10 times each).
  // Slice-outer loop keeps one 6.4 MB plane hot in L2 across its 10 iters.
  size_t plane = (size_t)N * 32;
  for (int s = 0; s < NSLICE; ++s) {
    const u16* xp = xb + s * plane;
    const u16* uin = xp;
    for (int k = 0; k < KPROP; ++k) {
      u16* uout = ((k & 1) ? u1 : u0) + s * plane;
      prop_slice_kernel<<<(N + 3) / 4, 256, 0, stream>>>(uin, xp, uout, rowptr, cols, N);
      uin = uout;
    }
  }

  // K=10 even -> final planes live in u1
  mlp_mfma_kernel<<<(N + 127) / 128, 256, 0, stream>>>(u1, W1P, b1, W2P, b2, out, N);
}

// Round 5
// 1499.016 us; speedup vs baseline: 1.5686x; 1.5686x over previous
//
#include <hip/hip_runtime.h>
#include <math.h>

typedef unsigned int uint32;
typedef unsigned short u16;
typedef __attribute__((ext_vector_type(8))) short short8;
typedef __attribute__((ext_vector_type(4))) float float4v;

#define CIN 128
#define HID 256
#define COUT 40
#define KPROP 10
#define ONE_MINUS_ALPHA 0.95f
#define PPR_ALPHA 0.05f
#define SCAN_CHUNK 1024
#define NSHARD 8

__device__ inline u16 f2bf(float f) {
  uint32 u = __float_as_uint(f);
  u += 0x7fffu + ((u >> 16) & 1u);
  return (u16)(u >> 16);
}
__device__ inline float bflo(uint32 w) { return __uint_as_float(w << 16); }
__device__ inline float bfhi(uint32 w) { return __uint_as_float(w & 0xffff0000u); }

// ---------------- CSR build ----------------

__global__ void hist_kernel(const int* __restrict__ src, int* __restrict__ cnt, int E) {
  int i = blockIdx.x * blockDim.x + threadIdx.x;
  int stride = gridDim.x * blockDim.x;
  for (; i < E; i += stride) atomicAdd(&cnt[src[i]], 1);
}

__global__ void chunk_sum_kernel(const int* __restrict__ cnt, int* __restrict__ bsum, int n) {
  __shared__ int smem[256];
  int b = blockIdx.x, t = threadIdx.x;
  int base = b * SCAN_CHUNK;
  int s = 0;
  for (int k = 0; k < 4; ++k) {
    int idx = base + t + k * 256;
    if (idx < n) s += cnt[idx];
  }
  smem[t] = s;
  __syncthreads();
  for (int off = 128; off > 0; off >>= 1) {
    if (t < off) smem[t] += smem[t + off];
    __syncthreads();
  }
  if (t == 0) bsum[b] = smem[0];
}

__global__ void bsum_scan_kernel(int* bsum, int nb) {
  __shared__ int sm[1024];
  int t = threadIdx.x;
  int v = (t < nb) ? bsum[t] : 0;
  sm[t] = v;
  __syncthreads();
  for (int off = 1; off < 1024; off <<= 1) {
    int add = (t >= off) ? sm[t - off] : 0;
    __syncthreads();
    sm[t] += add;
    __syncthreads();
  }
  if (t < nb) bsum[t] = sm[t] - v;  // exclusive
}

__global__ void chunk_scan_kernel(const int* __restrict__ cnt, const int* __restrict__ bsum,
                                  int* __restrict__ rowptr, int n) {
  __shared__ int smem[256];
  int b = blockIdx.x, t = threadIdx.x;
  int base = b * SCAN_CHUNK + t * 4;
  int v[4];
  for (int k = 0; k < 4; ++k) v[k] = (base + k < n) ? cnt[base + k] : 0;
  int s = v[0] + v[1] + v[2] + v[3];
  smem[t] = s;
  __syncthreads();
  for (int off = 1; off < 256; off <<= 1) {
    int add = (t >= off) ? smem[t - off] : 0;
    __syncthreads();
    smem[t] += add;
    __syncthreads();
  }
  int run = bsum[b] + smem[t] - s;
  for (int k = 0; k < 4; ++k) {
    run += v[k];
    if (base + k < n) rowptr[base + k + 1] = run;
  }
  if (b == 0 && t == 0) rowptr[0] = 0;
}

// XCD-sharded scatter: shard = blockIdx&7 (heuristic: consecutive blockIdx
// round-robin across the 8 XCDs). Shard s places only edges whose src falls
// in its node range, so each cols CSR region (~1.6 MB, fits one 4 MiB L2)
// is written by one XCD only -> each dirty line written back once.
__global__ void scatter_shard_kernel(const int* __restrict__ src, const int* __restrict__ dst,
                                     int* __restrict__ cursor, int* __restrict__ cols,
                                     int E, int shard_size) {
  int shard = blockIdx.x & (NSHARD - 1);
  int lo = shard * shard_size;
  int hi = lo + shard_size;
  int bi = blockIdx.x >> 3;
  int nb = gridDim.x >> 3;
  int i = bi * blockDim.x + threadIdx.x;
  int stride = nb * blockDim.x;
  for (; i < E; i += stride) {
    int s = src[i];
    if (s >= lo && s < hi) {
      int pos = atomicAdd(&cursor[s], 1);
      cols[pos] = dst[i];
    }
  }
}

// ---------------- prep: casts + weight packing ----------------

__global__ void cvt_bf16_kernel(const float* __restrict__ in, u16* __restrict__ out, int n4) {
  int i = blockIdx.x * blockDim.x + threadIdx.x;
  if (i < n4) {
    float4 v = ((const float4*)in)[i];
    uint2 p;
    p.x = (uint32)f2bf(v.x) | ((uint32)f2bf(v.y) << 16);
    p.y = (uint32)f2bf(v.z) | ((uint32)f2bf(v.w) << 16);
    ((uint2*)out)[i] = p;
  }
}

// W1P: B-fragment packed, 0.05 folded in. idx = ((kk*16+nt)*64+l)*8+j8
__global__ void pack_w1_kernel(const float* __restrict__ W1, u16* __restrict__ W1P) {
  int idx = blockIdx.x * blockDim.x + threadIdx.x;
  if (idx >= 4 * 16 * 64 * 8) return;
  int j8 = idx & 7;
  int l = (idx >> 3) & 63;
  int nt = (idx >> 9) & 15;
  int kk = idx >> 13;
  int k = kk * 32 + (l >> 4) * 8 + j8;
  int nn = nt * 16 + (l & 15);
  W1P[idx] = f2bf(PPR_ALPHA * W1[nn * CIN + k]);
}

// W2P: idx = ((kk2*3+nt2)*64+l)*8+j8
__global__ void pack_w2_kernel(const float* __restrict__ W2, u16* __restrict__ W2P) {
  int idx = blockIdx.x * blockDim.x + threadIdx.x;
  if (idx >= 8 * 3 * 64 * 8) return;
  int j8 = idx & 7;
  int l = (idx >> 3) & 63;
  int nt2 = (idx >> 9) % 3;
  int kk2 = (idx >> 9) / 3;
  int k = kk2 * 32 + (l >> 4) * 8 + j8;
  int o = nt2 * 16 + (l & 15);
  W2P[idx] = (o < COUT) ? f2bf(W2[o * HID + k]) : (u16)0;
}

// ---------------- propagation (bf16, wide gather, 4 loads in flight) ----------------
// wave per node. eg = lane>>4 (edge group 0..3), ch = lane&15 (16 B each).
// Main loop: 16 edges/iter via 4 independent uint4 gathers per lane.

__global__ __launch_bounds__(256) void prop_bf16_kernel(
    const u16* __restrict__ uin, const u16* __restrict__ xb, u16* __restrict__ uout,
    const int* __restrict__ rowptr, const int* __restrict__ cols, int n) {
  int wid = threadIdx.x >> 6;
  int lane = threadIdx.x & 63;
  int node = blockIdx.x * 4 + wid;
  if (node >= n) return;
  int eg = lane >> 4;
  int ch = lane & 15;
  int start = rowptr[node], end = rowptr[node + 1];
  const uint4* uw4 = (const uint4*)uin;

  float acc[8];
  if (eg == 0) {  // self-loop contribution, counted once
    uint4 s = uw4[(size_t)node * 16 + ch];
    acc[0] = bflo(s.x); acc[1] = bfhi(s.x);
    acc[2] = bflo(s.y); acc[3] = bfhi(s.y);
    acc[4] = bflo(s.z); acc[5] = bfhi(s.z);
    acc[6] = bflo(s.w); acc[7] = bfhi(s.w);
  } else {
#pragma unroll
    for (int j = 0; j < 8; ++j) acc[j] = 0.f;
  }

  int e = start;
  for (; e + 16 <= end; e += 16) {
    int d0 = cols[e + eg];
    int d1 = cols[e + 4 + eg];
    int d2 = cols[e + 8 + eg];
    int d3 = cols[e + 12 + eg];
    uint4 w0 = uw4[(size_t)d0 * 16 + ch];
    uint4 w1 = uw4[(size_t)d1 * 16 + ch];
    uint4 w2 = uw4[(size_t)d2 * 16 + ch];
    uint4 w3 = uw4[(size_t)d3 * 16 + ch];
    acc[0] += bflo(w0.x); acc[1] += bfhi(w0.x);
    acc[2] += bflo(w0.y); acc[3] += bfhi(w0.y);
    acc[4] += bflo(w0.z); acc[5] += bfhi(w0.z);
    acc[6] += bflo(w0.w); acc[7] += bfhi(w0.w);
    acc[0] += bflo(w1.x); acc[1] += bfhi(w1.x);
    acc[2] += bflo(w1.y); acc[3] += bfhi(w1.y);
    acc[4] += bflo(w1.z); acc[5] += bfhi(w1.z);
    acc[6] += bflo(w1.w); acc[7] += bfhi(w1.w);
    acc[0] += bflo(w2.x); acc[1] += bfhi(w2.x);
    acc[2] += bflo(w2.y); acc[3] += bfhi(w2.y);
    acc[4] += bflo(w2.z); acc[5] += bfhi(w2.z);
    acc[6] += bflo(w2.w); acc[7] += bfhi(w2.w);
    acc[0] += bflo(w3.x); acc[1] += bfhi(w3.x);
    acc[2] += bflo(w3.y); acc[3] += bfhi(w3.y);
    acc[4] += bflo(w3.z); acc[5] += bfhi(w3.z);
    acc[6] += bflo(w3.w); acc[7] += bfhi(w3.w);
  }
  for (; e + 8 <= end; e += 8) {
    int d0 = cols[e + eg];
    int d1 = cols[e + 4 + eg];
    uint4 w0 = uw4[(size_t)d0 * 16 + ch];
    uint4 w1 = uw4[(size_t)d1 * 16 + ch];
    acc[0] += bflo(w0.x); acc[1] += bfhi(w0.x);
    acc[2] += bflo(w0.y); acc[3] += bfhi(w0.y);
    acc[4] += bflo(w0.z); acc[5] += bfhi(w0.z);
    acc[6] += bflo(w0.w); acc[7] += bfhi(w0.w);
    acc[0] += bflo(w1.x); acc[1] += bfhi(w1.x);
    acc[2] += bflo(w1.y); acc[3] += bfhi(w1.y);
    acc[4] += bflo(w1.z); acc[5] += bfhi(w1.z);
    acc[6] += bflo(w1.w); acc[7] += bfhi(w1.w);
  }
  for (; e + 4 <= end; e += 4) {
    int d0 = cols[e + eg];
    uint4 w0 = uw4[(size_t)d0 * 16 + ch];
    acc[0] += bflo(w0.x); acc[1] += bfhi(w0.x);
    acc[2] += bflo(w0.y); acc[3] += bfhi(w0.y);
    acc[4] += bflo(w0.z); acc[5] += bfhi(w0.z);
    acc[6] += bflo(w0.w); acc[7] += bfhi(w0.w);
  }
  int rem = end - e;
  if (eg < rem) {
    int d0 = cols[e + eg];
    uint4 w0 = uw4[(size_t)d0 * 16 + ch];
    acc[0] += bflo(w0.x); acc[1] += bfhi(w0.x);
    acc[2] += bflo(w0.y); acc[3] += bfhi(w0.y);
    acc[4] += bflo(w0.z); acc[5] += bfhi(w0.z);
    acc[6] += bflo(w0.w); acc[7] += bfhi(w0.w);
  }

  // combine the 4 edge-groups (channels identical across groups)
#pragma unroll
  for (int j = 0; j < 8; ++j) acc[j] += __shfl_xor(acc[j], 16, 64);
#pragma unroll
  for (int j = 0; j < 8; ++j) acc[j] += __shfl_xor(acc[j], 32, 64);

  if (eg == 0) {
    float c = ONE_MINUS_ALPHA / (float)(end - start + 1);
    uint4 xw = ((const uint4*)xb)[(size_t)node * 16 + ch];
    uint4 r;
    r.x = (uint32)f2bf(bflo(xw.x) + c * acc[0]) | ((uint32)f2bf(bfhi(xw.x) + c * acc[1]) << 16);
    r.y = (uint32)f2bf(bflo(xw.y) + c * acc[2]) | ((uint32)f2bf(bfhi(xw.y) + c * acc[3]) << 16);
    r.z = (uint32)f2bf(bflo(xw.z) + c * acc[4]) | ((uint32)f2bf(bfhi(xw.z) + c * acc[5]) << 16);
    r.w = (uint32)f2bf(bflo(xw.w) + c * acc[6]) | ((uint32)f2bf(bfhi(xw.w) + c * acc[7]) << 16);
    ((uint4*)uout)[(size_t)node * 16 + ch] = r;
  }
}

// ---------------- fused MFMA MLP + log_softmax ----------------

#define HPAD 264

__global__ __launch_bounds__(256, 2) void mlp_mfma_kernel(
    const u16* __restrict__ u, const u16* __restrict__ W1P, const float* __restrict__ b1,
    const u16* __restrict__ W2P, const float* __restrict__ b2,
    float* __restrict__ out, int n) {
  __shared__ __align__(16) u16 hS[128][HPAD];

  int t = threadIdx.x;
  int w = t >> 6, l = t & 63;
  int lg = l >> 4;
  int ln = l & 15;
  int node0 = blockIdx.x * 128;

  short8 a1[2][4];
#pragma unroll
  for (int mt = 0; mt < 2; ++mt) {
    int node = node0 + w * 32 + mt * 16 + ln;
    if (node >= n) node = n - 1;
    const short8* urow = (const short8*)(u + (size_t)node * CIN);
#pragma unroll
    for (int kk = 0; kk < 4; ++kk) a1[mt][kk] = urow[kk * 4 + lg];
  }

  const short8* W1f = (const short8*)W1P;
  for (int nt = 0; nt < 16; ++nt) {
    short8 bfr[4];
#pragma unroll
    for (int kk = 0; kk < 4; ++kk) bfr[kk] = W1f[(kk * 16 + nt) * 64 + l];
    float bb = b1[nt * 16 + ln];
#pragma unroll
    for (int mt = 0; mt < 2; ++mt) {
      float4v c = {0.f, 0.f, 0.f, 0.f};
#pragma unroll
      for (int kk = 0; kk < 4; ++kk)
        c = __builtin_amdgcn_mfma_f32_16x16x32_bf16(a1[mt][kk], bfr[kk], c, 0, 0, 0);
#pragma unroll
      for (int r = 0; r < 4; ++r) {
        float h = fmaxf(c[r] + bb, 0.f);
        hS[w * 32 + mt * 16 + lg * 4 + r][nt * 16 + ln] = f2bf(h);
      }
    }
  }
  __syncthreads();

  const short8* W2f = (const short8*)W2P;
  float4v o2[2][3];
#pragma unroll
  for (int mt = 0; mt < 2; ++mt)
#pragma unroll
    for (int nt2 = 0; nt2 < 3; ++nt2) o2[mt][nt2] = (float4v){0.f, 0.f, 0.f, 0.f};
  for (int kk2 = 0; kk2 < 8; ++kk2) {
    short8 af[2];
#pragma unroll
    for (int mt = 0; mt < 2; ++mt)
      af[mt] = *(const short8*)&hS[w * 32 + mt * 16 + ln][kk2 * 32 + lg * 8];
    short8 bf0 = W2f[(kk2 * 3 + 0) * 64 + l];
    short8 bf1 = W2f[(kk2 * 3 + 1) * 64 + l];
    short8 bf2 = W2f[(kk2 * 3 + 2) * 64 + l];
#pragma unroll
    for (int mt = 0; mt < 2; ++mt) {
      o2[mt][0] = __builtin_amdgcn_mfma_f32_16x16x32_bf16(af[mt], bf0, o2[mt][0], 0, 0, 0);
      o2[mt][1] = __builtin_amdgcn_mfma_f32_16x16x32_bf16(af[mt], bf1, o2[mt][1], 0, 0, 0);
      o2[mt][2] = __builtin_amdgcn_mfma_f32_16x16x32_bf16(af[mt], bf2, o2[mt][2], 0, 0, 0);
    }
  }

  float b2v0 = b2[ln];
  float b2v1 = b2[16 + ln];
  bool v2 = (ln < 8);
  float b2v2 = v2 ? b2[32 + ln] : 0.f;
#pragma unroll
  for (int mt = 0; mt < 2; ++mt) {
#pragma unroll
    for (int r = 0; r < 4; ++r) {
      float x0 = o2[mt][0][r] + b2v0;
      float x1 = o2[mt][1][r] + b2v1;
      float x2 = v2 ? (o2[mt][2][r] + b2v2) : -INFINITY;
      float m = fmaxf(fmaxf(x0, x1), x2);
#pragma unroll
      for (int s = 1; s < 16; s <<= 1) m = fmaxf(m, __shfl_xor(m, s, 64));
      float es = __expf(x0 - m) + __expf(x1 - m) + (v2 ? __expf(x2 - m) : 0.f);
#pragma unroll
      for (int s = 1; s < 16; s <<= 1) es += __shfl_xor(es, s, 64);
      float lse = m + __logf(es);
      int node = node0 + w * 32 + mt * 16 + lg * 4 + r;
      if (node < n) {
        out[(size_t)node * COUT + ln] = x0 - lse;
        out[(size_t)node * COUT + 16 + ln] = x1 - lse;
        if (v2) out[(size_t)node * COUT + 32 + ln] = x2 - lse;
      }
    }
  }
}

// ---------------- launch ----------------

extern "C" void kernel_launch(void* const* d_in, const int* in_sizes, int n_in,
                              void* d_out, int out_size, void* d_ws, size_t ws_size,
                              hipStream_t stream) {
  const float* x = (const float*)d_in[0];
  const int* ei = (const int*)d_in[1];
  const float* W1 = (const float*)d_in[3];
  const float* b1 = (const float*)d_in[4];
  const float* W2 = (const float*)d_in[5];
  const float* b2 = (const float*)d_in[6];
  float* out = (float*)d_out;

  int N = in_sizes[0] / CIN;
  int E = in_sizes[1] / 2;
  const int* src = ei;
  const int* dst = ei + E;

  char* ws = (char*)d_ws;
  size_t off = 0;
  auto walloc = [&](size_t bytes) -> void* {
    void* p = ws + off;
    off += (bytes + 255) & ~(size_t)255;
    return p;
  };
  int* cnt = (int*)walloc((size_t)N * 4);
  int* rowptr = (int*)walloc(((size_t)N + 1) * 4);
  int* cursor = (int*)walloc((size_t)N * 4);
  int* bsum = (int*)walloc(1024 * 4);
  int* cols = (int*)walloc((size_t)E * 4);
  u16* W1P = (u16*)walloc((size_t)4 * 16 * 64 * 8 * 2);
  u16* W2P = (u16*)walloc((size_t)8 * 3 * 64 * 8 * 2);
  u16* xb = (u16*)walloc((size_t)N * CIN * 2);
  u16* u0 = (u16*)walloc((size_t)N * CIN * 2);
  u16* u1 = (u16*)walloc((size_t)N * CIN * 2);
  (void)ws_size; (void)n_in; (void)out_size;

  // CSR build (counting sort by src)
  hipMemsetAsync(cnt, 0, (size_t)N * 4, stream);
  hist_kernel<<<2048, 256, 0, stream>>>(src, cnt, E);
  int nchunks = (N + SCAN_CHUNK - 1) / SCAN_CHUNK;
  chunk_sum_kernel<<<nchunks, 256, 0, stream>>>(cnt, bsum, N);
  bsum_scan_kernel<<<1, 1024, 0, stream>>>(bsum, nchunks);
  chunk_scan_kernel<<<nchunks, 256, 0, stream>>>(cnt, bsum, rowptr, N);
  hipMemcpyAsync(cursor, rowptr, (size_t)N * 4, hipMemcpyDeviceToDevice, stream);
  int shard_size = (N + NSHARD - 1) / NSHARD;
  scatter_shard_kernel<<<2048, 256, 0, stream>>>(src, dst, cursor, cols, E, shard_size);

  // prep
  cvt_bf16_kernel<<<(N * CIN / 4 + 255) / 256, 256, 0, stream>>>(x, xb, N * CIN / 4);
  pack_w1_kernel<<<(4 * 16 * 64 * 8 + 255) / 256, 256, 0, stream>>>(W1, W1P);
  pack_w2_kernel<<<(8 * 3 * 64 * 8 + 255) / 256, 256, 0, stream>>>(W2, W2P);

  // Horner PPR: u <- x + 0.95 * P u  (10 times); 0.05 folded into W1P
  const u16* uin = xb;
  u16* ubufs[2] = {u0, u1};
  for (int k = 0; k < KPROP; ++k) {
    u16* uout = ubufs[k & 1];
    prop_bf16_kernel<<<(N + 3) / 4, 256, 0, stream>>>(uin, xb, uout, rowptr, cols, N);
    uin = uout;
  }

  mlp_mfma_kernel<<<(N + 127) / 128, 256, 0, stream>>>(uin, W1P, b1, W2P, b2, out, N);
}